// Round 1
// baseline (274.344 us; speedup 1.0000x reference)
//
#include <hip/hip_runtime.h>
#include <hip/hip_bf16.h>
#include <stdint.h>

// ConstrastiveLoss2: loss = (sum_i lse_row(i) + sum_j lse_col(j) - 2*sum_i diag(i)) / (2B)
// logits = tau * ftir @ raman^T, tau = min(exp(log_tau), 100), B=4096, D=512.
// Strategy: cast to bf16, fused MFMA GEMM computing per-tile (max,sumexp) partials
// for rows and cols (never materializing logits), fp32 diag, then combine.

typedef float f32x4 __attribute__((ext_vector_type(4)));
typedef __bf16 bf16x8 __attribute__((ext_vector_type(8)));
typedef __bf16 bf16x4 __attribute__((ext_vector_type(4)));

#define B_DIM 4096
#define D_DIM 512

__device__ __forceinline__ void gld_lds16(const void* g, void* l) {
  __builtin_amdgcn_global_load_lds(
      (const __attribute__((address_space(1))) unsigned int*)g,
      (__attribute__((address_space(3))) unsigned int*)l,
      16, 0, 0);
}

// ---------------- cast fp32 -> bf16 for both matrices ----------------
__global__ __launch_bounds__(256) void cast_kernel(
    const float* __restrict__ A, const float* __restrict__ Bm,
    __bf16* __restrict__ Abf, __bf16* __restrict__ Bbf) {
  int idx = blockIdx.x * blockDim.x + threadIdx.x;  // 0 .. 2*524288-1
  const int nq = (B_DIM * D_DIM) / 4;               // 524288 float4s per matrix
  const float4* src; bf16x4* dst; int i;
  if (idx < nq) { src = (const float4*)A;  dst = (bf16x4*)Abf; i = idx; }
  else          { src = (const float4*)Bm; dst = (bf16x4*)Bbf; i = idx - nq; }
  float4 v = src[i];
  bf16x4 o;
  o[0] = (__bf16)v.x; o[1] = (__bf16)v.y; o[2] = (__bf16)v.z; o[3] = (__bf16)v.w;
  dst[i] = o;
}

// ---------------- fp32 diagonal: acc -= 2 * tau * dot(ftir_i, raman_i) ----------------
__global__ __launch_bounds__(256) void diag_kernel(
    const float* __restrict__ A, const float* __restrict__ Bm,
    const float* __restrict__ log_tau, float* __restrict__ acc) {
  int gid  = blockIdx.x * blockDim.x + threadIdx.x;
  int row  = gid >> 6;
  int lane = gid & 63;
  const float4* a = (const float4*)(A  + (size_t)row * D_DIM);
  const float4* b = (const float4*)(Bm + (size_t)row * D_DIM);
  float4 a0 = a[lane], a1 = a[lane + 64];
  float4 b0 = b[lane], b1 = b[lane + 64];
  float s = a0.x*b0.x + a0.y*b0.y + a0.z*b0.z + a0.w*b0.w
          + a1.x*b1.x + a1.y*b1.y + a1.z*b1.z + a1.w*b1.w;
  #pragma unroll
  for (int off = 1; off < 64; off <<= 1) s += __shfl_xor(s, off);
  if (lane == 0) {
    float tau = fminf(__expf(log_tau[0]), 100.0f);
    atomicAdd(acc, -2.0f * tau * s);
  }
}

// ---------------- fused GEMM + per-tile row/col (max, sumexp) partials ----------------
// grid (32,32); 256 threads = 4 waves in 2x2; each wave: 64x64 via 4x4 of 16x16x32 MFMA.
// Partials: 64 chunks (32 blocks x 2 waves) per dimension, each chunk covers 64 entries.
__global__ __launch_bounds__(256) void gemm_lse_kernel(
    const __bf16* __restrict__ A, const __bf16* __restrict__ Bm,
    const float* __restrict__ log_tau,
    float* __restrict__ row_pmax, float* __restrict__ row_psum,
    float* __restrict__ col_pmax, float* __restrict__ col_psum) {
  __shared__ __bf16 Alds[128 * 32];
  __shared__ __bf16 Blds[128 * 32];
  const int bm = blockIdx.x, bn = blockIdx.y;
  const int t = threadIdx.x;
  const int lane = t & 63;
  const int w = t >> 6;
  const int wm = (w >> 1) * 64;   // wave row offset in 128-tile
  const int wn = (w & 1) * 64;    // wave col offset in 128-tile

  f32x4 acc[4][4] = {};

  // staging addresses: thread t loads 16B: row t>>2, cols (t&3)*8 .. +7 (half-tile per issue)
  const __bf16* Ag = A  + (size_t)(bm * 128 + (t >> 2)) * D_DIM + (t & 3) * 8;
  const __bf16* Bg = Bm + (size_t)(bn * 128 + (t >> 2)) * D_DIM + (t & 3) * 8;
  __bf16* Al = Alds + t * 8;  // == wave_base + lane*16B, contiguous in lane order
  __bf16* Bl = Blds + t * 8;

  for (int k0 = 0; k0 < D_DIM; k0 += 32) {
    gld_lds16(Ag + k0, Al);
    gld_lds16(Ag + 64 * D_DIM + k0, Al + 64 * 32);
    gld_lds16(Bg + k0, Bl);
    gld_lds16(Bg + 64 * D_DIM + k0, Bl + 64 * 32);
    __syncthreads();

    bf16x8 af[4], bfr[4];
    const int kgrp = (lane >> 4) * 8;
    const int rsel = lane & 15;
    #pragma unroll
    for (int mi = 0; mi < 4; ++mi)
      af[mi] = *(const bf16x8*)(Alds + (wm + mi * 16 + rsel) * 32 + kgrp);
    #pragma unroll
    for (int ni = 0; ni < 4; ++ni)
      bfr[ni] = *(const bf16x8*)(Blds + (wn + ni * 16 + rsel) * 32 + kgrp);
    #pragma unroll
    for (int mi = 0; mi < 4; ++mi)
      #pragma unroll
      for (int ni = 0; ni < 4; ++ni)
        acc[mi][ni] = __builtin_amdgcn_mfma_f32_16x16x32_bf16(af[mi], bfr[ni], acc[mi][ni], 0, 0, 0);
    __syncthreads();
  }

  // epilogue: scale by tau, reduce to per-row / per-col (max, sumexp) over this wave's 64x64
  const float tau = fminf(__expf(log_tau[0]), 100.0f);
  #pragma unroll
  for (int mi = 0; mi < 4; ++mi)
    #pragma unroll
    for (int ni = 0; ni < 4; ++ni)
      acc[mi][ni] *= tau;

  // C layout (verified m89): col = lane&15, row = (lane>>4)*4 + reg
  // --- rows: reduce across ni and across the 16 lanes sharing a row (masks 1,2,4,8) ---
  #pragma unroll
  for (int mi = 0; mi < 4; ++mi) {
    #pragma unroll
    for (int r = 0; r < 4; ++r) {
      float mx = fmaxf(fmaxf(acc[mi][0][r], acc[mi][1][r]),
                       fmaxf(acc[mi][2][r], acc[mi][3][r]));
      #pragma unroll
      for (int off = 1; off < 16; off <<= 1) mx = fmaxf(mx, __shfl_xor(mx, off));
      float s = 0.f;
      #pragma unroll
      for (int ni = 0; ni < 4; ++ni) s += __expf(acc[mi][ni][r] - mx);
      #pragma unroll
      for (int off = 1; off < 16; off <<= 1) s += __shfl_xor(s, off);
      if ((lane & 15) == 0) {
        int row   = bm * 128 + wm + mi * 16 + (lane >> 4) * 4 + r;
        int chunk = bn * 2 + (w & 1);
        row_pmax[chunk * B_DIM + row] = mx;
        row_psum[chunk * B_DIM + row] = s;
      }
    }
  }
  // --- cols: reduce across mi,r and across the 4 lane-groups (masks 16,32) ---
  #pragma unroll
  for (int ni = 0; ni < 4; ++ni) {
    float mx = -3.0e38f;
    #pragma unroll
    for (int mi = 0; mi < 4; ++mi)
      #pragma unroll
      for (int r = 0; r < 4; ++r) mx = fmaxf(mx, acc[mi][ni][r]);
    mx = fmaxf(mx, __shfl_xor(mx, 16));
    mx = fmaxf(mx, __shfl_xor(mx, 32));
    float s = 0.f;
    #pragma unroll
    for (int mi = 0; mi < 4; ++mi)
      #pragma unroll
      for (int r = 0; r < 4; ++r) s += __expf(acc[mi][ni][r] - mx);
    s += __shfl_xor(s, 16);
    s += __shfl_xor(s, 32);
    if (lane < 16) {
      int col   = bn * 128 + wn + ni * 16 + lane;
      int chunk = bm * 2 + (w >> 1);
      col_pmax[chunk * B_DIM + col] = mx;
      col_psum[chunk * B_DIM + col] = s;
    }
  }
}

// ---------------- combine 64 chunk-partials per row/col into lse, accumulate ----------------
__global__ __launch_bounds__(256) void combine_kernel(
    const float* __restrict__ row_pmax, const float* __restrict__ row_psum,
    const float* __restrict__ col_pmax, const float* __restrict__ col_psum,
    float* __restrict__ acc) {
  int gid  = blockIdx.x * blockDim.x + threadIdx.x;
  int item = gid >> 6;           // 0..8191 (4096 rows then 4096 cols)
  int lane = gid & 63;           // one chunk per lane
  const float* pm; const float* ps; int i;
  if (item < B_DIM) { pm = row_pmax; ps = row_psum; i = item; }
  else              { pm = col_pmax; ps = col_psum; i = item - B_DIM; }
  float m = pm[lane * B_DIM + i];
  float s = ps[lane * B_DIM + i];
  float M = m;
  #pragma unroll
  for (int off = 1; off < 64; off <<= 1) M = fmaxf(M, __shfl_xor(M, off));
  float S = s * __expf(m - M);
  #pragma unroll
  for (int off = 1; off < 64; off <<= 1) S += __shfl_xor(S, off);
  if (lane == 0) atomicAdd(acc, M + __logf(S));
}

__global__ void final_kernel(const float* __restrict__ acc, float* __restrict__ out) {
  if (threadIdx.x == 0) out[0] = acc[0] * (1.0f / 8192.0f);
}

// ---------------- launch ----------------
extern "C" void kernel_launch(void* const* d_in, const int* in_sizes, int n_in,
                              void* d_out, int out_size, void* d_ws, size_t ws_size,
                              hipStream_t stream) {
  const float* ftir    = (const float*)d_in[0];
  const float* raman   = (const float*)d_in[1];
  // d_in[2] = labels (int64) — unused by the reference output
  const float* log_tau = (const float*)d_in[3];
  float* out = (float*)d_out;

  char* ws = (char*)d_ws;
  // ws layout (bytes): Abf 4MiB | Bbf 4MiB | row_pmax 1MiB | row_psum 1MiB |
  //                    col_pmax 1MiB | col_psum 1MiB | acc 4B            (~12.6 MiB)
  __bf16* Abf     = (__bf16*)(ws);
  __bf16* Bbf     = (__bf16*)(ws + (4u << 20));
  float* row_pmax = (float*)(ws + (8u << 20));
  float* row_psum = (float*)(ws + (9u << 20));
  float* col_pmax = (float*)(ws + (10u << 20));
  float* col_psum = (float*)(ws + (11u << 20));
  float* acc      = (float*)(ws + (12u << 20));

  hipMemsetAsync(acc, 0, sizeof(float), stream);
  cast_kernel<<<4096, 256, 0, stream>>>(ftir, raman, Abf, Bbf);
  diag_kernel<<<1024, 256, 0, stream>>>(ftir, raman, log_tau, acc);
  gemm_lse_kernel<<<dim3(32, 32), 256, 0, stream>>>(Abf, Bbf, log_tau,
                                                    row_pmax, row_psum, col_pmax, col_psum);
  combine_kernel<<<2048, 256, 0, stream>>>(row_pmax, row_psum, col_pmax, col_psum, acc);
  final_kernel<<<1, 64, 0, stream>>>(acc, out);
}

// Round 2
// 138.466 us; speedup vs baseline: 1.9813x; 1.9813x over previous
//
#include <hip/hip_runtime.h>
#include <hip/hip_bf16.h>
#include <stdint.h>

// ConstrastiveLoss2: loss = (sum_i lse_row(i) + sum_j lse_col(j) - 2*tau*sum_e a[e]b[e]) / (2B)
// logits = tau * ftir @ raman^T, tau = min(exp(log_tau), 100), B=4096, D=512.
// R2: item-major partials (coalesced combine reads), hierarchical reductions
// (64 atomics instead of 8192+4096), diag fused into the cast kernel.

typedef float f32x4 __attribute__((ext_vector_type(4)));
typedef __bf16 bf16x8 __attribute__((ext_vector_type(8)));
typedef __bf16 bf16x4 __attribute__((ext_vector_type(4)));

#define B_DIM 4096
#define D_DIM 512
#define NCHUNK 64   // partial chunks per row/col (32 blocks x 2 waves)

__device__ __forceinline__ void gld_lds16(const void* g, void* l) {
  __builtin_amdgcn_global_load_lds(
      (const __attribute__((address_space(1))) unsigned int*)g,
      (__attribute__((address_space(3))) unsigned int*)l,
      16, 0, 0);
}

// ---------------- cast fp32 -> bf16 + fused diag elementwise-product partials ----------------
// grid 512 x 256, grid-stride x4 over 524288 float4 pairs. One partial per block.
__global__ __launch_bounds__(256) void cast_diag_kernel(
    const float* __restrict__ A, const float* __restrict__ Bm,
    __bf16* __restrict__ Abf, __bf16* __restrict__ Bbf,
    float* __restrict__ diagp) {
  const float4* A4 = (const float4*)A;
  const float4* B4 = (const float4*)Bm;
  bf16x4* Ab4 = (bf16x4*)Abf;
  bf16x4* Bb4 = (bf16x4*)Bbf;
  int idx = blockIdx.x * 256 + threadIdx.x;
  float local = 0.f;
  #pragma unroll
  for (int it = 0; it < 4; ++it, idx += 512 * 256) {
    float4 va = A4[idx], vb = B4[idx];
    bf16x4 oa, ob;
    oa[0] = (__bf16)va.x; oa[1] = (__bf16)va.y; oa[2] = (__bf16)va.z; oa[3] = (__bf16)va.w;
    ob[0] = (__bf16)vb.x; ob[1] = (__bf16)vb.y; ob[2] = (__bf16)vb.z; ob[3] = (__bf16)vb.w;
    Ab4[idx] = oa; Bb4[idx] = ob;
    local += va.x*vb.x + va.y*vb.y + va.z*vb.z + va.w*vb.w;
  }
  #pragma unroll
  for (int off = 1; off < 64; off <<= 1) local += __shfl_xor(local, off);
  __shared__ float red[4];
  int w = threadIdx.x >> 6, lane = threadIdx.x & 63;
  if (lane == 0) red[w] = local;
  __syncthreads();
  if (threadIdx.x == 0)
    diagp[blockIdx.x] = red[0] + red[1] + red[2] + red[3];
}

// ---------------- fused GEMM + per-tile row/col (max, sumexp) partials ----------------
// grid (32,32); 256 threads = 4 waves in 2x2; each wave: 64x64 via 4x4 of 16x16x32 MFMA.
__global__ __launch_bounds__(256) void gemm_lse_kernel(
    const __bf16* __restrict__ A, const __bf16* __restrict__ Bm,
    const float* __restrict__ log_tau,
    float* __restrict__ row_pmax, float* __restrict__ row_psum,
    float* __restrict__ col_pmax, float* __restrict__ col_psum) {
  __shared__ __bf16 Alds[128 * 32];
  __shared__ __bf16 Blds[128 * 32];
  const int bm = blockIdx.x, bn = blockIdx.y;
  const int t = threadIdx.x;
  const int lane = t & 63;
  const int w = t >> 6;
  const int wm = (w >> 1) * 64;   // wave row offset in 128-tile
  const int wn = (w & 1) * 64;    // wave col offset in 128-tile

  f32x4 acc[4][4] = {};

  const __bf16* Ag = A  + (size_t)(bm * 128 + (t >> 2)) * D_DIM + (t & 3) * 8;
  const __bf16* Bg = Bm + (size_t)(bn * 128 + (t >> 2)) * D_DIM + (t & 3) * 8;
  __bf16* Al = Alds + t * 8;
  __bf16* Bl = Blds + t * 8;

  for (int k0 = 0; k0 < D_DIM; k0 += 32) {
    gld_lds16(Ag + k0, Al);
    gld_lds16(Ag + 64 * D_DIM + k0, Al + 64 * 32);
    gld_lds16(Bg + k0, Bl);
    gld_lds16(Bg + 64 * D_DIM + k0, Bl + 64 * 32);
    __syncthreads();

    bf16x8 af[4], bfr[4];
    const int kgrp = (lane >> 4) * 8;
    const int rsel = lane & 15;
    #pragma unroll
    for (int mi = 0; mi < 4; ++mi)
      af[mi] = *(const bf16x8*)(Alds + (wm + mi * 16 + rsel) * 32 + kgrp);
    #pragma unroll
    for (int ni = 0; ni < 4; ++ni)
      bfr[ni] = *(const bf16x8*)(Blds + (wn + ni * 16 + rsel) * 32 + kgrp);
    #pragma unroll
    for (int mi = 0; mi < 4; ++mi)
      #pragma unroll
      for (int ni = 0; ni < 4; ++ni)
        acc[mi][ni] = __builtin_amdgcn_mfma_f32_16x16x32_bf16(af[mi], bfr[ni], acc[mi][ni], 0, 0, 0);
    __syncthreads();
  }

  const float tau = fminf(__expf(log_tau[0]), 100.0f);
  #pragma unroll
  for (int mi = 0; mi < 4; ++mi)
    #pragma unroll
    for (int ni = 0; ni < 4; ++ni)
      acc[mi][ni] *= tau;

  // C layout (verified m89): col = lane&15, row = (lane>>4)*4 + reg
  // --- rows: reduce across ni and the 16 lanes sharing a row; item-major store ---
  #pragma unroll
  for (int mi = 0; mi < 4; ++mi) {
    #pragma unroll
    for (int r = 0; r < 4; ++r) {
      float mx = fmaxf(fmaxf(acc[mi][0][r], acc[mi][1][r]),
                       fmaxf(acc[mi][2][r], acc[mi][3][r]));
      #pragma unroll
      for (int off = 1; off < 16; off <<= 1) mx = fmaxf(mx, __shfl_xor(mx, off));
      float s = 0.f;
      #pragma unroll
      for (int ni = 0; ni < 4; ++ni) s += __expf(acc[mi][ni][r] - mx);
      #pragma unroll
      for (int off = 1; off < 16; off <<= 1) s += __shfl_xor(s, off);
      if ((lane & 15) == 0) {
        int row   = bm * 128 + wm + mi * 16 + (lane >> 4) * 4 + r;
        int chunk = bn * 2 + (w & 1);
        row_pmax[row * NCHUNK + chunk] = mx;
        row_psum[row * NCHUNK + chunk] = s;
      }
    }
  }
  // --- cols: reduce across mi,r and the 4 lane-groups; item-major store ---
  #pragma unroll
  for (int ni = 0; ni < 4; ++ni) {
    float mx = -3.0e38f;
    #pragma unroll
    for (int mi = 0; mi < 4; ++mi)
      #pragma unroll
      for (int r = 0; r < 4; ++r) mx = fmaxf(mx, acc[mi][ni][r]);
    mx = fmaxf(mx, __shfl_xor(mx, 16));
    mx = fmaxf(mx, __shfl_xor(mx, 32));
    float s = 0.f;
    #pragma unroll
    for (int mi = 0; mi < 4; ++mi)
      #pragma unroll
      for (int r = 0; r < 4; ++r) s += __expf(acc[mi][ni][r] - mx);
    s += __shfl_xor(s, 16);
    s += __shfl_xor(s, 32);
    if (lane < 16) {
      int col   = bn * 128 + wn + ni * 16 + lane;
      int chunk = bm * 2 + (w >> 1);
      col_pmax[col * NCHUNK + chunk] = mx;
      col_psum[col * NCHUNK + chunk] = s;
    }
  }
}

// ---------------- combine: 64 blocks, each 128 items; one atomic per block ----------------
__global__ __launch_bounds__(256) void combine_kernel(
    const float* __restrict__ row_pmax, const float* __restrict__ row_psum,
    const float* __restrict__ col_pmax, const float* __restrict__ col_psum,
    const float* __restrict__ diagp, const float* __restrict__ log_tau,
    float* __restrict__ acc) {
  const int w = threadIdx.x >> 6, lane = threadIdx.x & 63;
  float local = 0.f;
  #pragma unroll 1
  for (int j = 0; j < 32; ++j) {
    int item = blockIdx.x * 128 + w * 32 + j;    // 0..4095 rows, 4096..8191 cols
    const float* pm; const float* ps; int i;
    if (item < B_DIM) { pm = row_pmax; ps = row_psum; i = item; }
    else              { pm = col_pmax; ps = col_psum; i = item - B_DIM; }
    float m = pm[i * NCHUNK + lane];
    float s = ps[i * NCHUNK + lane];
    float M = m;
    #pragma unroll
    for (int off = 1; off < 64; off <<= 1) M = fmaxf(M, __shfl_xor(M, off));
    float S = s * __expf(m - M);
    #pragma unroll
    for (int off = 1; off < 64; off <<= 1) S += __shfl_xor(S, off);
    local += M + __logf(S);     // identical in all lanes after xor-reduce
  }
  // wave 0 additionally folds in its slice of the diag partials (512 total / 64 blocks = 8)
  if (w == 0) {
    float tau = fminf(__expf(log_tau[0]), 100.0f);
    float d = (lane < 8) ? diagp[blockIdx.x * 8 + lane] : 0.f;
    #pragma unroll
    for (int off = 1; off < 8; off <<= 1) d += __shfl_xor(d, off);
    local += -2.0f * tau * d;   // same in lanes 0..7; lane 0 is the representative
  }
  __shared__ float red[4];
  if (lane == 0) red[w] = local;
  __syncthreads();
  if (threadIdx.x == 0)
    atomicAdd(acc, red[0] + red[1] + red[2] + red[3]);
}

__global__ void final_kernel(const float* __restrict__ acc, float* __restrict__ out) {
  if (threadIdx.x == 0) out[0] = acc[0] * (1.0f / 8192.0f);
}

// ---------------- launch ----------------
extern "C" void kernel_launch(void* const* d_in, const int* in_sizes, int n_in,
                              void* d_out, int out_size, void* d_ws, size_t ws_size,
                              hipStream_t stream) {
  const float* ftir    = (const float*)d_in[0];
  const float* raman   = (const float*)d_in[1];
  // d_in[2] = labels (int64) — unused by the reference output
  const float* log_tau = (const float*)d_in[3];
  float* out = (float*)d_out;

  char* ws = (char*)d_ws;
  // ws layout: Abf 4MiB | Bbf 4MiB | row_pmax 1MiB | row_psum 1MiB |
  //            col_pmax 1MiB | col_psum 1MiB | diagp 2KiB | acc 4B
  __bf16* Abf     = (__bf16*)(ws);
  __bf16* Bbf     = (__bf16*)(ws + (4u << 20));
  float* row_pmax = (float*)(ws + (8u << 20));
  float* row_psum = (float*)(ws + (9u << 20));
  float* col_pmax = (float*)(ws + (10u << 20));
  float* col_psum = (float*)(ws + (11u << 20));
  float* diagp    = (float*)(ws + (12u << 20));
  float* acc      = (float*)(ws + (12u << 20) + 4096);

  hipMemsetAsync(acc, 0, sizeof(float), stream);
  cast_diag_kernel<<<512, 256, 0, stream>>>(ftir, raman, Abf, Bbf, diagp);
  gemm_lse_kernel<<<dim3(32, 32), 256, 0, stream>>>(Abf, Bbf, log_tau,
                                                    row_pmax, row_psum, col_pmax, col_psum);
  combine_kernel<<<64, 256, 0, stream>>>(row_pmax, row_psum, col_pmax, col_psum,
                                         diagp, log_tau, acc);
  final_kernel<<<1, 64, 0, stream>>>(acc, out);
}

// Round 3
// 105.225 us; speedup vs baseline: 2.6072x; 1.3159x over previous
//
#include <hip/hip_runtime.h>
#include <hip/hip_bf16.h>
#include <stdint.h>

// ConstrastiveLoss2: loss = (sum_i lse_row(i) + sum_j lse_col(j) - 2*tau*sum_e a[e]b[e]) / (2B)
// logits = tau * ftir @ raman^T, tau = min(exp(log_tau), 100), B=4096, D=512.
// R3: XOR-swizzled bf16 layout (conflict-free ds_read_b128), BK=64 (8 iters),
// shuffle-free block-cooperative epilogue, chunk-major partials (NCHUNK=32).

typedef float f32x4 __attribute__((ext_vector_type(4)));
typedef __bf16 bf16x8 __attribute__((ext_vector_type(8)));
typedef __bf16 bf16x4 __attribute__((ext_vector_type(4)));

#define B_DIM 4096
#define D_DIM 512
#define NCHUNK 32   // partial chunks per row/col (one per 128-tile in the other dim)

__device__ __forceinline__ void gld_lds16(const void* g, void* l) {
  __builtin_amdgcn_global_load_lds(
      (const __attribute__((address_space(1))) unsigned int*)g,
      (__attribute__((address_space(3))) unsigned int*)l,
      16, 0, 0);
}

// ---------------- cast fp32 -> bf16 (k-block XOR swizzle) + fused diag partials ----------------
// Swizzled layout: within each row's aligned 64-element chunk, the 8-element
// k-block G is stored at position G ^ (row & 7). After the linear
// global_load_lds copy, LDS inherits this layout -> conflict-free ds_read_b128.
__global__ __launch_bounds__(256) void cast_diag_kernel(
    const float* __restrict__ A, const float* __restrict__ Bm,
    __bf16* __restrict__ Abf, __bf16* __restrict__ Bbf,
    float* __restrict__ diagp) {
  const float4* A4 = (const float4*)A;
  const float4* B4 = (const float4*)Bm;
  bf16x4* Ab4 = (bf16x4*)Abf;
  bf16x4* Bb4 = (bf16x4*)Bbf;
  int idx = blockIdx.x * 256 + threadIdx.x;
  float local = 0.f;
  #pragma unroll
  for (int it = 0; it < 4; ++it, idx += 512 * 256) {
    int row = idx >> 7, el4 = idx & 127;          // el4: bits[6:4]=chunk [3:1]=G [0]=half
    int swzG = ((el4 >> 1) ^ row) & 7;
    int el4p = (el4 & 0x71) | (swzG << 1);
    int pidx = row * 128 + el4p;
    float4 va = A4[idx], vb = B4[idx];
    bf16x4 oa, ob;
    oa[0] = (__bf16)va.x; oa[1] = (__bf16)va.y; oa[2] = (__bf16)va.z; oa[3] = (__bf16)va.w;
    ob[0] = (__bf16)vb.x; ob[1] = (__bf16)vb.y; ob[2] = (__bf16)vb.z; ob[3] = (__bf16)vb.w;
    Ab4[pidx] = oa; Bb4[pidx] = ob;
    local += va.x*vb.x + va.y*vb.y + va.z*vb.z + va.w*vb.w;
  }
  #pragma unroll
  for (int off = 1; off < 64; off <<= 1) local += __shfl_xor(local, off);
  __shared__ float red[4];
  int w = threadIdx.x >> 6, lane = threadIdx.x & 63;
  if (lane == 0) red[w] = local;
  __syncthreads();
  if (threadIdx.x == 0)
    diagp[blockIdx.x] = red[0] + red[1] + red[2] + red[3];
}

// ---------------- fused GEMM + per-tile row/col (max, sumexp) partials ----------------
// grid (32,32); 4 waves in 2x2; wave computes 64x64 via 4x4 of 16x16x32 MFMA.
// BK=64 per LDS stage. Epilogue: shuffle-free, LDS-cooperative.
__global__ __launch_bounds__(256) void gemm_lse_kernel(
    const __bf16* __restrict__ A, const __bf16* __restrict__ Bm,
    const float* __restrict__ log_tau,
    float* __restrict__ row_pmax, float* __restrict__ row_psum,
    float* __restrict__ col_pmax, float* __restrict__ col_psum) {
  __shared__ char smem[34816];                 // union: staging 32KB | rowbuf 33KB
  __bf16* Alds = (__bf16*)smem;                // 128 rows x 64 el (swizzled) = 16KB
  __bf16* Blds = (__bf16*)(smem + 16384);      // 16KB
  const int bm = blockIdx.x, bn = blockIdx.y;
  const int t = threadIdx.x;
  const int lane = t & 63;
  const int w = t >> 6;
  const int wm = (w >> 1) * 64, wn = (w & 1) * 64;
  const int q = lane >> 4, c16 = lane & 15, swz = c16 & 7;

  f32x4 acc[4][4] = {};

  // staging: thread t -> row (t>>3)+32*i, k-block t&7 (16B each); LDS dest linear in t.
  const char* Ag = (const char*)(A + (size_t)(bm * 128 + (t >> 3)) * D_DIM + (t & 7) * 8);
  const char* Bg = (const char*)(Bm + (size_t)(bn * 128 + (t >> 3)) * D_DIM + (t & 7) * 8);
  char* Al = (char*)Alds + t * 16;
  char* Bl = (char*)Blds + t * 16;

  for (int kt = 0; kt < 8; ++kt) {
    const char* ag = Ag + kt * 128;            // 64 el = 128 B per kt
    const char* bg = Bg + kt * 128;
    #pragma unroll
    for (int i = 0; i < 4; ++i) {              // 32 rows per issue (1024 B global row stride)
      gld_lds16(ag + i * 32 * 1024, Al + i * 4096);
      gld_lds16(bg + i * 32 * 1024, Bl + i * 4096);
    }
    __syncthreads();
    const __bf16* Abase = Alds + (wm + c16) * 64;
    const __bf16* Bbase = Blds + (wn + c16) * 64;
    #pragma unroll
    for (int h = 0; h < 2; ++h) {
      const int kb = ((h << 2) | q) ^ swz;     // physical k-block (swizzle undo)
      bf16x8 af[4], bfr[4];
      #pragma unroll
      for (int mi = 0; mi < 4; ++mi)
        af[mi] = *(const bf16x8*)(Abase + mi * 1024 + kb * 8);
      #pragma unroll
      for (int ni = 0; ni < 4; ++ni)
        bfr[ni] = *(const bf16x8*)(Bbase + ni * 1024 + kb * 8);
      #pragma unroll
      for (int mi = 0; mi < 4; ++mi)
        #pragma unroll
        for (int ni = 0; ni < 4; ++ni)
          acc[mi][ni] = __builtin_amdgcn_mfma_f32_16x16x32_bf16(af[mi], bfr[ni], acc[mi][ni], 0, 0, 0);
    }
    __syncthreads();
  }

  const float tau = fminf(__expf(log_tau[0]), 100.0f);
  #pragma unroll
  for (int mi = 0; mi < 4; ++mi)
    #pragma unroll
    for (int ni = 0; ni < 4; ++ni)
      acc[mi][ni] *= tau;

  // C layout (m89): col = wn + ni*16 + c16, row = wm + mi*16 + q*4 + r.
  // ---- rows phase 1: per-lane reduce over 4 ni values, scatter to rowbuf[128][33] ----
  float2* rbuf = (float2*)smem;
  #pragma unroll
  for (int mi = 0; mi < 4; ++mi)
    #pragma unroll
    for (int r = 0; r < 4; ++r) {
      float v0 = acc[mi][0][r], v1 = acc[mi][1][r], v2 = acc[mi][2][r], v3 = acc[mi][3][r];
      float m = fmaxf(fmaxf(v0, v1), fmaxf(v2, v3));
      float s = __expf(v0 - m) + __expf(v1 - m) + __expf(v2 - m) + __expf(v3 - m);
      int R = wm + mi * 16 + q * 4 + r;
      rbuf[R * 33 + (w & 1) * 16 + c16] = make_float2(m, s);
    }
  __syncthreads();
  // ---- rows phase 2: thread t<128 combines row t's 32 partials ----
  if (t < 128) {
    float M = rbuf[t * 33].x;
    #pragma unroll
    for (int x = 1; x < 32; ++x) M = fmaxf(M, rbuf[t * 33 + x].x);
    float S = 0.f;
    #pragma unroll
    for (int x = 0; x < 32; ++x) { float2 p = rbuf[t * 33 + x]; S += p.y * __expf(p.x - M); }
    row_pmax[bn * B_DIM + bm * 128 + t] = M;   // chunk-major: coalesced here AND in combine
    row_psum[bn * B_DIM + bm * 128 + t] = S;
  }
  __syncthreads();
  // ---- cols phase 1: per-lane reduce over 16 (mi,r) values, scatter to cbuf[128][9] ----
  float2* cbuf = (float2*)smem;
  #pragma unroll
  for (int ni = 0; ni < 4; ++ni) {
    float m = -3.0e38f;
    #pragma unroll
    for (int mi = 0; mi < 4; ++mi)
      #pragma unroll
      for (int r = 0; r < 4; ++r) m = fmaxf(m, acc[mi][ni][r]);
    float s = 0.f;
    #pragma unroll
    for (int mi = 0; mi < 4; ++mi)
      #pragma unroll
      for (int r = 0; r < 4; ++r) s += __expf(acc[mi][ni][r] - m);
    int C = wn + ni * 16 + c16;
    cbuf[C * 9 + (w >> 1) * 4 + q] = make_float2(m, s);
  }
  __syncthreads();
  // ---- cols phase 2: thread t<128 combines col t's 8 partials ----
  if (t < 128) {
    float M = cbuf[t * 9].x;
    #pragma unroll
    for (int y = 1; y < 8; ++y) M = fmaxf(M, cbuf[t * 9 + y].x);
    float S = 0.f;
    #pragma unroll
    for (int y = 0; y < 8; ++y) { float2 p = cbuf[t * 9 + y]; S += p.y * __expf(p.x - M); }
    col_pmax[bm * B_DIM + bn * 128 + t] = M;
    col_psum[bm * B_DIM + bn * 128 + t] = S;
  }
}

// ---------------- combine: thread per item, coalesced chunk-major reads ----------------
__global__ __launch_bounds__(256) void combine_kernel(
    const float* __restrict__ row_pmax, const float* __restrict__ row_psum,
    const float* __restrict__ col_pmax, const float* __restrict__ col_psum,
    const float* __restrict__ diagp, const float* __restrict__ log_tau,
    float* __restrict__ acc) {
  const int t = threadIdx.x;
  const int item = blockIdx.x * 256 + t;       // 0..4095 rows, 4096..8191 cols
  const float* pm; const float* ps; int i;
  if (item < B_DIM) { pm = row_pmax; ps = row_psum; i = item; }
  else              { pm = col_pmax; ps = col_psum; i = item - B_DIM; }
  float M = pm[i];
  #pragma unroll
  for (int k = 1; k < NCHUNK; ++k) M = fmaxf(M, pm[k * B_DIM + i]);
  float S = 0.f;
  #pragma unroll
  for (int k = 0; k < NCHUNK; ++k) S += ps[k * B_DIM + i] * __expf(pm[k * B_DIM + i] - M);
  float local = M + __logf(S);
  if (blockIdx.x == 0) {                       // fold diag partials (512) into block 0
    float tau = fminf(__expf(log_tau[0]), 100.0f);
    local += -2.0f * tau * (diagp[t] + diagp[t + 256]);
  }
  #pragma unroll
  for (int off = 1; off < 64; off <<= 1) local += __shfl_xor(local, off);
  __shared__ float red[4];
  int w = t >> 6, lane = t & 63;
  if (lane == 0) red[w] = local;
  __syncthreads();
  if (t == 0) atomicAdd(acc, red[0] + red[1] + red[2] + red[3]);
}

__global__ void final_kernel(const float* __restrict__ acc, float* __restrict__ out) {
  if (threadIdx.x == 0) out[0] = acc[0] * (1.0f / 8192.0f);
}

// ---------------- launch ----------------
extern "C" void kernel_launch(void* const* d_in, const int* in_sizes, int n_in,
                              void* d_out, int out_size, void* d_ws, size_t ws_size,
                              hipStream_t stream) {
  const float* ftir    = (const float*)d_in[0];
  const float* raman   = (const float*)d_in[1];
  // d_in[2] = labels (int64) — unused by the reference output
  const float* log_tau = (const float*)d_in[3];
  float* out = (float*)d_out;

  char* ws = (char*)d_ws;
  // ws layout: Abf 4MiB | Bbf 4MiB | row_pmax 512K | row_psum 512K |
  //            col_pmax 512K | col_psum 512K | diagp 2K | acc 4B
  __bf16* Abf     = (__bf16*)(ws);
  __bf16* Bbf     = (__bf16*)(ws + (4u << 20));
  float* row_pmax = (float*)(ws + (8u << 20));
  float* row_psum = (float*)(ws + (8u << 20) + (512u << 10));
  float* col_pmax = (float*)(ws + (9u << 20));
  float* col_psum = (float*)(ws + (9u << 20) + (512u << 10));
  float* diagp    = (float*)(ws + (10u << 20));
  float* acc      = (float*)(ws + (10u << 20) + 4096);

  hipMemsetAsync(acc, 0, sizeof(float), stream);
  cast_diag_kernel<<<512, 256, 0, stream>>>(ftir, raman, Abf, Bbf, diagp);
  gemm_lse_kernel<<<dim3(32, 32), 256, 0, stream>>>(Abf, Bbf, log_tau,
                                                    row_pmax, row_psum, col_pmax, col_psum);
  combine_kernel<<<32, 256, 0, stream>>>(row_pmax, row_psum, col_pmax, col_psum,
                                         diagp, log_tau, acc);
  final_kernel<<<1, 64, 0, stream>>>(acc, out);
}

// Round 4
// 102.817 us; speedup vs baseline: 2.6683x; 1.0234x over previous
//
#include <hip/hip_runtime.h>
#include <hip/hip_bf16.h>
#include <stdint.h>

// ConstrastiveLoss2: loss = (sum_i lse_row(i) + sum_j lse_col(j) - 2*tau*sum_e a[e]b[e]) / (2B)
// logits = tau * ftir @ raman^T, tau = min(exp(log_tau), 100), B=4096, D=512.
// R4: 3 dispatches (cast zeros acc/counter; combine absorbs final via atomic
// counter), XCD-aware block swizzle in the GEMM (per-XCD 3MB L2 working set).

typedef float f32x4 __attribute__((ext_vector_type(4)));
typedef __bf16 bf16x8 __attribute__((ext_vector_type(8)));
typedef __bf16 bf16x4 __attribute__((ext_vector_type(4)));

#define B_DIM 4096
#define D_DIM 512
#define NCHUNK 32   // partial chunks per row/col (one per 128-tile in the other dim)

__device__ __forceinline__ void gld_lds16(const void* g, void* l) {
  __builtin_amdgcn_global_load_lds(
      (const __attribute__((address_space(1))) unsigned int*)g,
      (__attribute__((address_space(3))) unsigned int*)l,
      16, 0, 0);
}

// ---------------- cast fp32 -> bf16 (k-block XOR swizzle) + fused diag partials ----------------
// Swizzled layout: within each row's aligned 64-element chunk, the 8-element
// k-block G is stored at position G ^ (row & 7). After the linear
// global_load_lds copy, LDS inherits this layout -> conflict-free ds_read_b128.
// Also zeroes the accumulator and the combine counter (ws is poisoned 0xAA).
__global__ __launch_bounds__(256) void cast_diag_kernel(
    const float* __restrict__ A, const float* __restrict__ Bm,
    __bf16* __restrict__ Abf, __bf16* __restrict__ Bbf,
    float* __restrict__ diagp, float* __restrict__ acc,
    unsigned* __restrict__ counter) {
  if (blockIdx.x == 0 && threadIdx.x == 0) { acc[0] = 0.f; counter[0] = 0u; }
  const float4* A4 = (const float4*)A;
  const float4* B4 = (const float4*)Bm;
  bf16x4* Ab4 = (bf16x4*)Abf;
  bf16x4* Bb4 = (bf16x4*)Bbf;
  int idx = blockIdx.x * 256 + threadIdx.x;
  float local = 0.f;
  #pragma unroll
  for (int it = 0; it < 4; ++it, idx += 512 * 256) {
    int row = idx >> 7, el4 = idx & 127;          // el4: bits[6:4]=chunk [3:1]=G [0]=half
    int swzG = ((el4 >> 1) ^ row) & 7;
    int el4p = (el4 & 0x71) | (swzG << 1);
    int pidx = row * 128 + el4p;
    float4 va = A4[idx], vb = B4[idx];
    bf16x4 oa, ob;
    oa[0] = (__bf16)va.x; oa[1] = (__bf16)va.y; oa[2] = (__bf16)va.z; oa[3] = (__bf16)va.w;
    ob[0] = (__bf16)vb.x; ob[1] = (__bf16)vb.y; ob[2] = (__bf16)vb.z; ob[3] = (__bf16)vb.w;
    Ab4[pidx] = oa; Bb4[pidx] = ob;
    local += va.x*vb.x + va.y*vb.y + va.z*vb.z + va.w*vb.w;
  }
  #pragma unroll
  for (int off = 1; off < 64; off <<= 1) local += __shfl_xor(local, off);
  __shared__ float red[4];
  int w = threadIdx.x >> 6, lane = threadIdx.x & 63;
  if (lane == 0) red[w] = local;
  __syncthreads();
  if (threadIdx.x == 0)
    diagp[blockIdx.x] = red[0] + red[1] + red[2] + red[3];
}

// ---------------- fused GEMM + per-tile row/col (max, sumexp) partials ----------------
// 1024 blocks (XCD-swizzled to 8x16 bm x bn clusters); 4 waves in 2x2;
// wave computes 64x64 via 4x4 of 16x16x32 MFMA. BK=64. Shuffle-free epilogue.
__global__ __launch_bounds__(256) void gemm_lse_kernel(
    const __bf16* __restrict__ A, const __bf16* __restrict__ Bm,
    const float* __restrict__ log_tau,
    float* __restrict__ row_pmax, float* __restrict__ row_psum,
    float* __restrict__ col_pmax, float* __restrict__ col_psum) {
  __shared__ char smem[34816];                 // union: staging 32KB | rowbuf 33.8KB
  __bf16* Alds = (__bf16*)smem;                // 128 rows x 64 el (swizzled) = 16KB
  __bf16* Blds = (__bf16*)(smem + 16384);      // 16KB
  // XCD swizzle: blk%8 ~ XCD id; each XCD gets an 8(bm) x 16(bn) cluster ->
  // per-XCD L2 working set = 8 A-panels + 16 B-panels = 3 MB < 4 MB.
  const int blk = blockIdx.x;
  const int xcd = blk & 7, local = blk >> 3;
  const int bm = (xcd & 3) * 8 + (local & 7);
  const int bn = (xcd >> 2) * 16 + (local >> 3);
  const int t = threadIdx.x;
  const int lane = t & 63;
  const int w = t >> 6;
  const int wm = (w >> 1) * 64, wn = (w & 1) * 64;
  const int q = lane >> 4, c16 = lane & 15, swz = c16 & 7;

  f32x4 acc[4][4] = {};

  // staging: thread t -> row (t>>3)+32*i, k-block t&7 (16B each); LDS dest linear in t.
  const char* Ag = (const char*)(A + (size_t)(bm * 128 + (t >> 3)) * D_DIM + (t & 7) * 8);
  const char* Bg = (const char*)(Bm + (size_t)(bn * 128 + (t >> 3)) * D_DIM + (t & 7) * 8);
  char* Al = (char*)Alds + t * 16;
  char* Bl = (char*)Blds + t * 16;

  for (int kt = 0; kt < 8; ++kt) {
    const char* ag = Ag + kt * 128;            // 64 el = 128 B per kt
    const char* bg = Bg + kt * 128;
    #pragma unroll
    for (int i = 0; i < 4; ++i) {              // 32 rows per issue (1024 B global row stride)
      gld_lds16(ag + i * 32 * 1024, Al + i * 4096);
      gld_lds16(bg + i * 32 * 1024, Bl + i * 4096);
    }
    __syncthreads();
    const __bf16* Abase = Alds + (wm + c16) * 64;
    const __bf16* Bbase = Blds + (wn + c16) * 64;
    #pragma unroll
    for (int h = 0; h < 2; ++h) {
      const int kb = ((h << 2) | q) ^ swz;     // physical k-block (swizzle undo)
      bf16x8 af[4], bfr[4];
      #pragma unroll
      for (int mi = 0; mi < 4; ++mi)
        af[mi] = *(const bf16x8*)(Abase + mi * 1024 + kb * 8);
      #pragma unroll
      for (int ni = 0; ni < 4; ++ni)
        bfr[ni] = *(const bf16x8*)(Bbase + ni * 1024 + kb * 8);
      #pragma unroll
      for (int mi = 0; mi < 4; ++mi)
        #pragma unroll
        for (int ni = 0; ni < 4; ++ni)
          acc[mi][ni] = __builtin_amdgcn_mfma_f32_16x16x32_bf16(af[mi], bfr[ni], acc[mi][ni], 0, 0, 0);
    }
    __syncthreads();
  }

  const float tau = fminf(__expf(log_tau[0]), 100.0f);
  #pragma unroll
  for (int mi = 0; mi < 4; ++mi)
    #pragma unroll
    for (int ni = 0; ni < 4; ++ni)
      acc[mi][ni] *= tau;

  // C layout (m89): col = wn + ni*16 + c16, row = wm + mi*16 + q*4 + r.
  // ---- rows phase 1: per-lane reduce over 4 ni values, scatter to rowbuf[128][33] ----
  float2* rbuf = (float2*)smem;
  #pragma unroll
  for (int mi = 0; mi < 4; ++mi)
    #pragma unroll
    for (int r = 0; r < 4; ++r) {
      float v0 = acc[mi][0][r], v1 = acc[mi][1][r], v2 = acc[mi][2][r], v3 = acc[mi][3][r];
      float m = fmaxf(fmaxf(v0, v1), fmaxf(v2, v3));
      float s = __expf(v0 - m) + __expf(v1 - m) + __expf(v2 - m) + __expf(v3 - m);
      int R = wm + mi * 16 + q * 4 + r;
      rbuf[R * 33 + (w & 1) * 16 + c16] = make_float2(m, s);
    }
  __syncthreads();
  // ---- rows phase 2: thread t<128 combines row t's 32 partials ----
  if (t < 128) {
    float M = rbuf[t * 33].x;
    #pragma unroll
    for (int x = 1; x < 32; ++x) M = fmaxf(M, rbuf[t * 33 + x].x);
    float S = 0.f;
    #pragma unroll
    for (int x = 0; x < 32; ++x) { float2 p = rbuf[t * 33 + x]; S += p.y * __expf(p.x - M); }
    row_pmax[bn * B_DIM + bm * 128 + t] = M;   // chunk-major: coalesced here AND in combine
    row_psum[bn * B_DIM + bm * 128 + t] = S;
  }
  __syncthreads();
  // ---- cols phase 1: per-lane reduce over 16 (mi,r) values, scatter to cbuf[128][9] ----
  float2* cbuf = (float2*)smem;
  #pragma unroll
  for (int ni = 0; ni < 4; ++ni) {
    float m = -3.0e38f;
    #pragma unroll
    for (int mi = 0; mi < 4; ++mi)
      #pragma unroll
      for (int r = 0; r < 4; ++r) m = fmaxf(m, acc[mi][ni][r]);
    float s = 0.f;
    #pragma unroll
    for (int mi = 0; mi < 4; ++mi)
      #pragma unroll
      for (int r = 0; r < 4; ++r) s += __expf(acc[mi][ni][r] - m);
    int C = wn + ni * 16 + c16;
    cbuf[C * 9 + (w >> 1) * 4 + q] = make_float2(m, s);
  }
  __syncthreads();
  // ---- cols phase 2: thread t<128 combines col t's 8 partials ----
  if (t < 128) {
    float M = cbuf[t * 9].x;
    #pragma unroll
    for (int y = 1; y < 8; ++y) M = fmaxf(M, cbuf[t * 9 + y].x);
    float S = 0.f;
    #pragma unroll
    for (int y = 0; y < 8; ++y) { float2 p = cbuf[t * 9 + y]; S += p.y * __expf(p.x - M); }
    col_pmax[bm * B_DIM + bn * 128 + t] = M;
    col_psum[bm * B_DIM + bn * 128 + t] = S;
  }
}

// ---------------- combine: thread per item; last block (counter) writes d_out ----------------
__global__ __launch_bounds__(256) void combine_kernel(
    const float* __restrict__ row_pmax, const float* __restrict__ row_psum,
    const float* __restrict__ col_pmax, const float* __restrict__ col_psum,
    const float* __restrict__ diagp, const float* __restrict__ log_tau,
    float* __restrict__ acc, unsigned* __restrict__ counter,
    float* __restrict__ out) {
  const int t = threadIdx.x;
  const int item = blockIdx.x * 256 + t;       // 0..4095 rows, 4096..8191 cols
  const float* pm; const float* ps; int i;
  if (item < B_DIM) { pm = row_pmax; ps = row_psum; i = item; }
  else              { pm = col_pmax; ps = col_psum; i = item - B_DIM; }
  float M = pm[i];
  #pragma unroll
  for (int k = 1; k < NCHUNK; ++k) M = fmaxf(M, pm[k * B_DIM + i]);
  float S = 0.f;
  #pragma unroll
  for (int k = 0; k < NCHUNK; ++k) S += ps[k * B_DIM + i] * __expf(pm[k * B_DIM + i] - M);
  float local = M + __logf(S);
  if (blockIdx.x == 0) {                       // fold diag partials (512) into block 0
    float tau = fminf(__expf(log_tau[0]), 100.0f);
    local += -2.0f * tau * (diagp[t] + diagp[t + 256]);
  }
  #pragma unroll
  for (int off = 1; off < 64; off <<= 1) local += __shfl_xor(local, off);
  __shared__ float red[4];
  int w = t >> 6, lane = t & 63;
  if (lane == 0) red[w] = local;
  __syncthreads();
  if (t == 0) {
    atomicAdd(acc, red[0] + red[1] + red[2] + red[3]);
    __threadfence();
    unsigned old = atomicAdd(counter, 1u);
    if (old == 31u) {                          // last of the 32 blocks: finalize
      float v = atomicAdd(acc, 0.0f);          // coherent read after all adds
      out[0] = v * (1.0f / 8192.0f);
    }
  }
}

// ---------------- launch ----------------
extern "C" void kernel_launch(void* const* d_in, const int* in_sizes, int n_in,
                              void* d_out, int out_size, void* d_ws, size_t ws_size,
                              hipStream_t stream) {
  const float* ftir    = (const float*)d_in[0];
  const float* raman   = (const float*)d_in[1];
  // d_in[2] = labels (int64) — unused by the reference output
  const float* log_tau = (const float*)d_in[3];
  float* out = (float*)d_out;

  char* ws = (char*)d_ws;
  // ws layout: Abf 4MiB | Bbf 4MiB | row_pmax 512K | row_psum 512K |
  //            col_pmax 512K | col_psum 512K | diagp 2K | acc 4B | counter 4B
  __bf16* Abf     = (__bf16*)(ws);
  __bf16* Bbf     = (__bf16*)(ws + (4u << 20));
  float* row_pmax = (float*)(ws + (8u << 20));
  float* row_psum = (float*)(ws + (8u << 20) + (512u << 10));
  float* col_pmax = (float*)(ws + (9u << 20));
  float* col_psum = (float*)(ws + (9u << 20) + (512u << 10));
  float* diagp    = (float*)(ws + (10u << 20));
  float* acc      = (float*)(ws + (10u << 20) + 4096);
  unsigned* cnt   = (unsigned*)(ws + (10u << 20) + 4096 + 4);

  cast_diag_kernel<<<512, 256, 0, stream>>>(ftir, raman, Abf, Bbf, diagp, acc, cnt);
  gemm_lse_kernel<<<1024, 256, 0, stream>>>(Abf, Bbf, log_tau,
                                            row_pmax, row_psum, col_pmax, col_psum);
  combine_kernel<<<32, 256, 0, stream>>>(row_pmax, row_psum, col_pmax, col_psum,
                                         diagp, log_tau, acc, cnt, out);
}